// Round 16
// baseline (179.099 us; speedup 1.0000x reference)
//
#include <hip/hip_runtime.h>

#define B_ 8
#define L_ 2048
#define E_ 256
#define H_ 4
#define D_ 64

typedef __bf16 bf16;
typedef __bf16 bf16x8 __attribute__((ext_vector_type(8)));
typedef __bf16 bf16x4 __attribute__((ext_vector_type(4)));
typedef float  f32x4  __attribute__((ext_vector_type(4)));
typedef float  f32x16 __attribute__((ext_vector_type(16)));

// Ŝ = (q·k)/8 * log2(e); softmax entirely in exp2 domain.
#define QSCALE 0.1803368801111244f

__device__ __forceinline__ float fexp2(float x) { return __builtin_amdgcn_exp2f(x); }
__device__ __forceinline__ float flog2(float x) { return __builtin_amdgcn_logf(x); }

// Barrier that drains LDS ops but NOT global loads (vmcnt stays in flight).
// Safe when all cross-wave communication is through LDS.
__device__ __forceinline__ void barrier_lds() {
    asm volatile("s_waitcnt lgkmcnt(0)" ::: "memory");
    __builtin_amdgcn_s_barrier();
}

// ---------------------------------------------------------------------------
// Kernel 0: repack weights to bf16 Wcat[768][256]
// (rows 0..511 = in_proj_w q,k rows; rows 512..767 = W_gnn^T).
// convert_x deleted: proj now self-converts x from f32.
// ---------------------------------------------------------------------------
__global__ void prep_kernel(const float* __restrict__ in_proj_w,
                            const float* __restrict__ W_gnn,
                            bf16* __restrict__ Wcat) {
    int r = blockIdx.x;
    int e = threadIdx.x;
    float v = (r < 512) ? in_proj_w[r * E_ + e] : W_gnn[e * E_ + (r - 512)];
    Wcat[r * E_ + e] = (bf16)v;
}

// ---------------------------------------------------------------------------
// Kernel 2: projections (r13 LDS-staged structure + XCD pinning + f32 self-
// convert). Flat grid 768: b=flat&7 pins each batch's x rows + outputs to one
// XCD's L2 (Wcat 384KB replicates per XCD). af built from f32 x directly.
// ---------------------------------------------------------------------------
__global__ __launch_bounds__(256, 2) void proj_kernel(
    const float* __restrict__ x, const bf16* __restrict__ Wcat,
    const float* __restrict__ in_proj_b, const float* __restrict__ B_gnn,
    bf16* __restrict__ Qs, bf16* __restrict__ Ks, bf16* __restrict__ XWT) {
    __shared__ bf16 ldsW[2][256 * 36];
    int tid  = threadIdx.x;
    int lane = tid & 63, wave = tid >> 6;
    int l16  = lane & 15, quad = lane >> 4;

    int flat = blockIdx.x;
    int b   = flat & 7;          // batch == XCD
    int s   = flat >> 3;         // 0..95
    int by  = s >> 5;            // 0..2
    int mtl = s & 31;            // m-tile within batch
    int m0  = b * 2048 + mtl * 64 + wave * 16;
    int n0  = by * 256;

    f32x4 acc[16];
#pragma unroll
    for (int i = 0; i < 16; i++) acc[i] = (f32x4){0.f, 0.f, 0.f, 0.f};

    // lane's x row slice, converted f32 -> bf16 in-register
    bf16x8 af[8];
    const float* xrow = x + (size_t)(m0 + l16) * E_;
#pragma unroll
    for (int ks = 0; ks < 8; ks++) {
        f32x4 lo = *(const f32x4*)&xrow[ks * 32 + quad * 8];
        f32x4 hi = *(const f32x4*)&xrow[ks * 32 + quad * 8 + 4];
        bf16x8 v;
#pragma unroll
        for (int j = 0; j < 4; j++) { v[j] = (bf16)lo[j]; v[4 + j] = (bf16)hi[j]; }
        af[ks] = v;
    }

    const bf16* Wb = Wcat + (size_t)n0 * E_;

#pragma unroll
    for (int it = 0; it < 4; it++) {
        int idx = it * 256 + tid;
        int n = idx >> 2, c8 = (idx & 3) * 8;
        *(bf16x8*)&ldsW[0][n * 36 + c8] = *(const bf16x8*)&Wb[(size_t)n * E_ + c8];
    }
    __syncthreads();

    int cur = 0;
    for (int ks = 0; ks < 8; ks++) {
        bf16x8 pw[4];
        if (ks < 7) {
#pragma unroll
            for (int it = 0; it < 4; it++) {
                int idx = it * 256 + tid;
                int n = idx >> 2, c8 = (idx & 3) * 8;
                pw[it] = *(const bf16x8*)&Wb[(size_t)n * E_ + (ks + 1) * 32 + c8];
            }
        }
#pragma unroll
        for (int nt = 0; nt < 16; nt++) {
            bf16x8 bfv = *(const bf16x8*)&ldsW[cur][(nt * 16 + l16) * 36 + quad * 8];
            acc[nt] = __builtin_amdgcn_mfma_f32_16x16x32_bf16(af[ks], bfv, acc[nt], 0, 0, 0);
        }
        if (ks < 7) {
#pragma unroll
            for (int it = 0; it < 4; it++) {
                int idx = it * 256 + tid;
                int n = idx >> 2, c8 = (idx & 3) * 8;
                *(bf16x8*)&ldsW[cur ^ 1][n * 36 + c8] = pw[it];
            }
        }
        barrier_lds();
        cur ^= 1;
    }

#pragma unroll
    for (int nt = 0; nt < 16; nt++) {
        int n = n0 + nt * 16 + l16;
        if (by == 0) {
            float bias = in_proj_b[n];
#pragma unroll
            for (int r = 0; r < 4; r++) {
                int m = m0 + quad * 4 + r;
                Qs[(size_t)m * E_ + n] = (bf16)((acc[nt][r] + bias) * QSCALE);
            }
        } else if (by == 1) {
            float bias = in_proj_b[n];
            int col = n - 256;
#pragma unroll
            for (int r = 0; r < 4; r++) {
                int m = m0 + quad * 4 + r;
                Ks[(size_t)m * E_ + col] = (bf16)(acc[nt][r] + bias);
            }
        } else {
            int nc = n - 512;
            float bias = B_gnn[nc];
            int m = m0 + quad * 4;
            int bb = m >> 11, l = m & 2047;
            bf16x4 pk;
#pragma unroll
            for (int r = 0; r < 4; r++) pk[r] = (bf16)(acc[nt][r] + bias);
            *(bf16x4*)&XWT[((size_t)bb * E_ + nc) * L_ + l] = pk;
        }
    }
}

// ---------------------------------------------------------------------------
// Kernel 3: softmax stats (r13 128-key dbuf structure + XCD pinning).
// Flat grid 512: b=flat&7 -> each XCD's L2 holds its batch's Ks+Qs (2 MB);
// the 16 qt-blocks sharing one (h,b) K-slice re-stage from L2, not L3
// (was: ~512 MB of cross-XCD L3 traffic).
// ---------------------------------------------------------------------------
__global__ __launch_bounds__(256, 4) void stats_kernel(
    const bf16* __restrict__ Qs, const bf16* __restrict__ Ks,
    float* __restrict__ o) {
    __shared__ bf16 ldsK[2][128 * 72];
    int tid  = threadIdx.x;
    int lane = tid & 63, wave = tid >> 6;
    int r32  = lane & 31, half = lane >> 5;

    int flat = blockIdx.x;
    int b    = flat & 7;         // batch == XCD
    int rest = flat >> 3;        // 0..63
    int qt   = rest & 15;
    int h    = rest >> 4;        // 0..3
    int q0 = qt * 128 + wave * 32;

    bf16x8 qa[4];
    const bf16* qrow = Qs + ((size_t)b * L_ + q0 + r32) * E_ + h * D_;
#pragma unroll
    for (int c = 0; c < 4; c++) qa[c] = *(const bf16x8*)&qrow[c * 16 + half * 8];

    float lsum[16];
#pragma unroll
    for (int i = 0; i < 16; i++) lsum[i] = 0.f;

    const bf16* Kb = Ks + (size_t)b * L_ * E_ + h * D_;

#pragma unroll
    for (int it = 0; it < 4; it++) {
        int idx = it * 256 + tid;
        int key = idx >> 3, dc = (idx & 7) * 8;
        *(bf16x8*)&ldsK[0][key * 72 + dc] =
            *(const bf16x8*)&Kb[(size_t)key * E_ + dc];
    }
    __syncthreads();

    int cur = 0;
    for (int kt = 0; kt < 16; kt++) {
        bf16x8 pk[4];
        if (kt < 15) {
#pragma unroll
            for (int it = 0; it < 4; it++) {
                int idx = it * 256 + tid;
                pk[it] = *(const bf16x8*)&Kb[(size_t)((kt + 1) * 128 + (idx >> 3)) * E_ + (idx & 7) * 8];
            }
        }
#pragma unroll
        for (int nt = 0; nt < 4; nt++) {
            f32x16 S = {};
#pragma unroll
            for (int c = 0; c < 4; c++) {
                bf16x8 kb = *(const bf16x8*)&ldsK[cur][(nt * 32 + r32) * 72 + c * 16 + half * 8];
                S = __builtin_amdgcn_mfma_f32_32x32x16_bf16(qa[c], kb, S, 0, 0, 0);
            }
#pragma unroll
            for (int i = 0; i < 16; i++) lsum[i] += fexp2(S[i]);
        }
        if (kt < 15) {
#pragma unroll
            for (int it = 0; it < 4; it++) {
                int idx = it * 256 + tid;
                *(bf16x8*)&ldsK[cur ^ 1][(idx >> 3) * 72 + (idx & 7) * 8] = pk[it];
            }
        }
        barrier_lds();
        cur ^= 1;
    }
#pragma unroll
    for (int i = 0; i < 16; i++) {
        float v = lsum[i];
        v += __shfl_xor(v, 1); v += __shfl_xor(v, 2); v += __shfl_xor(v, 4);
        v += __shfl_xor(v, 8); v += __shfl_xor(v, 16);
        lsum[i] = v;
    }
    if (r32 == 0) {
        float* op = o + ((size_t)(b * H_ + h)) * L_ + q0;
#pragma unroll
        for (int i = 0; i < 16; i++) {
            int row = (i & 3) + 8 * (i >> 2) + 4 * half;
            op[row] = -(2.0f + flog2(lsum[i]));
        }
    }
}

// ---------------------------------------------------------------------------
// Kernel 4: pass 2, producer-consumer (r15 structure, 63.4 us measured:
// VGPR 92, WRITE 16.4 MB pure output). Micro-change only: oh[h] folded into
// the QK MFMA C-initializer (s starts at oh[h]) -- removes 64 v_adds per
// interval on the heavier producer wave. Schedule untouched.
// ---------------------------------------------------------------------------
__global__ void __launch_bounds__(512) __attribute__((amdgpu_waves_per_eu(2, 2)))
pass2_kernel(
    const bf16* __restrict__ Qs, const bf16* __restrict__ Ks,
    const bf16* __restrict__ XWT, const float* __restrict__ o,
    float* __restrict__ out) {
    __shared__ alignas(16) unsigned char smem[159744];
    bf16* ldsK0  = (bf16*)smem;              // [64][264]
    bf16* ldsK1  = (bf16*)(smem + 33792);    // [64][264]
    bf16* ldsXW0 = (bf16*)(smem + 67584);    // [256][72]
    bf16* ldsXW1 = (bf16*)(smem + 104448);   // [256][72]
    bf16* ldsP0  = (bf16*)(smem + 141312);   // [64][72]
    bf16* ldsP1  = (bf16*)(smem + 150528);   // [64][72]

    int tid  = threadIdx.x;
    int lane = tid & 63, wave = tid >> 6;
    int l32  = lane & 31, half = lane >> 5;

    int flat = blockIdx.x;
    int b  = flat & 7;          // batch == XCD (L2 pin)
    int qt = flat >> 3;         // 0..31
    int q0 = qt * 64;

    const bf16* Kb = Ks + (size_t)b * L_ * E_;
    const bf16* Xb = XWT + (size_t)b * E_ * L_;

    // prologue: all 8 waves stage K_0 -> ldsK0
#pragma unroll
    for (int it = 0; it < 4; it++) {
        int idx = it * 512 + tid;
        int key = idx >> 5, col = (idx & 31) * 8;
        *(bf16x8*)&ldsK0[key * 264 + col] =
            *(const bf16x8*)&Kb[(size_t)key * E_ + col];
    }
    __syncthreads();

    if (wave < 4) {
        // ================= PRODUCER (QK + softmax + XW staging) ============
        int pqh = wave & 1, pkh = wave >> 1;
        int qw = q0 + pqh * 32 + l32;

        bf16x8 qf[4][4];
        const bf16* qrow = Qs + ((size_t)b * L_ + qw) * E_;
#pragma unroll
        for (int h = 0; h < H_; h++)
#pragma unroll
            for (int c = 0; c < 4; c++)
                qf[h][c] = *(const bf16x8*)&qrow[h * 64 + c * 16 + half * 8];

        float oh[4];
#pragma unroll
        for (int h = 0; h < H_; h++)
            oh[h] = o[((size_t)(b * H_ + h)) * L_ + qw];

        for (int kt = 0; kt < 32; kt++) {
            bf16* kcur = (kt & 1) ? ldsK1  : ldsK0;
            bf16* xcur = (kt & 1) ? ldsXW1 : ldsXW0;
            bf16* pcur = (kt & 1) ? ldsP1  : ldsP0;

            // issue XW_kt loads (written this interval, read by consumers at kt+1)
            bf16x8 pxf[8];
#pragma unroll
            for (int it = 0; it < 8; it++) {
                int idx = it * 256 + tid;
                int n = idx >> 3, kc8 = (idx & 7) * 8;
                pxf[it] = *(const bf16x8*)&Xb[(size_t)n * L_ + kt * 64 + kc8];
            }

            // QK_kt: s initialized to oh[h] (fold of the softmax offset);
            // P = sum_h exp2(s)
            f32x16 P = {};
#pragma unroll
            for (int h = 0; h < H_; h++) {
                f32x16 s;
#pragma unroll
                for (int r = 0; r < 16; r++) s[r] = oh[h];
#pragma unroll
                for (int c = 0; c < 4; c++) {
                    bf16x8 ka = *(const bf16x8*)&kcur[(pkh * 32 + l32) * 264 + h * 64 + c * 16 + half * 8];
                    s = __builtin_amdgcn_mfma_f32_32x32x16_bf16(ka, qf[h][c], s, 0, 0, 0);
                }
#pragma unroll
                for (int r = 0; r < 16; r++) P[r] += fexp2(s[r]);
            }

            // P_kt at TRUE key indices (regs 4g..4g+3 -> keys 8g+4*half+0..3)
#pragma unroll
            for (int g = 0; g < 4; g++) {
                bf16x4 pk;
#pragma unroll
                for (int j = 0; j < 4; j++) pk[j] = (bf16)P[4 * g + j];
                *(bf16x4*)&pcur[(pqh * 32 + l32) * 72 + pkh * 32 + g * 8 + half * 4] = pk;
            }

            // XW_kt -> xcur (vmcnt wait here, covered by QK above)
#pragma unroll
            for (int it = 0; it < 8; it++) {
                int idx = it * 256 + tid;
                int n = idx >> 3, kc8 = (idx & 7) * 8;
                *(bf16x8*)&xcur[n * 72 + kc8] = pxf[it];
            }
            barrier_lds();
        }
        // producers done (no LDS use after final barrier)
    } else {
        // ================= CONSUMER (PV lag-1 + K staging) =================
        int cw = wave - 4;
        int cqh = cw & 1, cnh = cw >> 1;
        int ctid = tid - 256;   // 0..255

        f32x16 zero = {};
        f32x16 acc[4];
#pragma unroll
        for (int i = 0; i < 4; i++) acc[i] = zero;

        for (int kt = 0; kt < 32; kt++) {
            bf16* knext = (kt & 1) ? ldsK0  : ldsK1;   // slot (kt+1)&1
            bf16* xprev = (kt & 1) ? ldsXW0 : ldsXW1;  // slot (kt-1)&1
            bf16* pprev = (kt & 1) ? ldsP0  : ldsP1;   // slot (kt-1)&1

            // issue K_{kt+1} loads (written this interval into knext)
            bf16x8 pkf[8];
            if (kt < 31) {
#pragma unroll
                for (int it = 0; it < 8; it++) {
                    int idx = it * 256 + ctid;
                    int key = idx >> 5, col = (idx & 31) * 8;
                    pkf[it] = *(const bf16x8*)&Kb[(size_t)((kt + 1) * 64 + key) * E_ + col];
                }
            }

            // PV_{kt-1}: O[32q x 128n] += P[32q x 64k] @ XW[64k x 128n]
            if (kt > 0) {
#pragma unroll
                for (int kc = 0; kc < 4; kc++) {
                    bf16x8 pa = *(const bf16x8*)&pprev[(cqh * 32 + l32) * 72 + kc * 16 + half * 8];
#pragma unroll
                    for (int nt = 0; nt < 4; nt++) {
                        bf16x8 xw = *(const bf16x8*)&xprev[(cnh * 128 + nt * 32 + l32) * 72 + kc * 16 + half * 8];
                        acc[nt] = __builtin_amdgcn_mfma_f32_32x32x16_bf16(pa, xw, acc[nt], 0, 0, 0);
                    }
                }
            }

            // K_{kt+1} -> knext (vmcnt wait here, covered by PV above)
            if (kt < 31) {
#pragma unroll
                for (int it = 0; it < 8; it++) {
                    int idx = it * 256 + ctid;
                    int key = idx >> 5, col = (idx & 31) * 8;
                    *(bf16x8*)&knext[key * 264 + col] = pkf[it];
                }
            }
            barrier_lds();
        }

        // epilogue: PV_31 (P_31/XW_31 in slot 1, drained at final barrier)
#pragma unroll
        for (int kc = 0; kc < 4; kc++) {
            bf16x8 pa = *(const bf16x8*)&ldsP1[(cqh * 32 + l32) * 72 + kc * 16 + half * 8];
#pragma unroll
            for (int nt = 0; nt < 4; nt++) {
                bf16x8 xw = *(const bf16x8*)&ldsXW1[(cnh * 128 + nt * 32 + l32) * 72 + kc * 16 + half * 8];
                acc[nt] = __builtin_amdgcn_mfma_f32_32x32x16_bf16(pa, xw, acc[nt], 0, 0, 0);
            }
        }

        // direct store: consumer owns disjoint 32q x 128n of out[B,L,E]
        float* Ob = out + ((size_t)b * L_ + q0 + cqh * 32) * E_ + cnh * 128;
#pragma unroll
        for (int nt = 0; nt < 4; nt++)
#pragma unroll
            for (int r = 0; r < 16; r++) {
                int row = (r & 3) + 8 * (r >> 2) + 4 * half;
                Ob[(size_t)row * E_ + nt * 32 + l32] = acc[nt][r];
            }
    }
}

// ---------------------------------------------------------------------------
extern "C" void kernel_launch(void* const* d_in, const int* in_sizes, int n_in,
                              void* d_out, int out_size, void* d_ws, size_t ws_size,
                              hipStream_t stream) {
    const float* x   = (const float*)d_in[0];
    const float* ipw = (const float*)d_in[1];
    const float* ipb = (const float*)d_in[2];
    const float* wg  = (const float*)d_in[3];
    const float* bg  = (const float*)d_in[4];

    char* ws = (char*)d_ws;
    bf16*  Qs   = (bf16*)(ws);
    bf16*  Ks   = (bf16*)(ws + 8388608);
    bf16*  XWT  = (bf16*)(ws + 16777216);
    float* o    = (float*)(ws + 25165824);
    bf16*  Wcat = (bf16*)(ws + 33816576);

    prep_kernel<<<768, 256, 0, stream>>>(ipw, wg, Wcat);
    proj_kernel<<<768, 256, 0, stream>>>(x, Wcat, ipb, bg, Qs, Ks, XWT);
    stats_kernel<<<512, 256, 0, stream>>>(Qs, Ks, o);
    pass2_kernel<<<256, 512, 0, stream>>>(Qs, Ks, XWT, o, (float*)d_out);
}